// Round 1
// baseline (191.019 us; speedup 1.0000x reference)
//
#include <hip/hip_runtime.h>

typedef _Float16 half8 __attribute__((ext_vector_type(8)));
typedef float floatx4 __attribute__((ext_vector_type(4)));

#define BB 8
#define CC 64
#define HH 128
#define WW 256
#define DD 64
#define NROW 2            // (b,h) rows per block
#define GRID 512          // 2 blocks per CU; NROW*GRID == BB*HH

// out[b,d,h,w] = (1/64) sum_c L[b,c,h,w] * R[b,c,h,w-d], 0 where w<d.
// Banded Gram via mfma_f32_16x16x32_f16 (see R3/R4 comments for the algebra).
// R5: software-pipelined rows — next row's 16 dwordx4 are issued into
// registers BEFORE the current row's MFMA+stores.
// R6: occupancy fix. rocprof showed MfmaUtil 1.2%, VALUBusy 3.9%, HBM 21%,
// Occupancy 18% -> latency-bound: 1 block/CU meant every __syncthreads()
// (which drains vmcnt(0), incl. the 40 scalar stores/thread) stalled the
// whole CU. 72 KiB LDS x2 = 144 <= 160 KiB and VGPR(92->128-gran) allows
// 16 waves/CU, so run 2 blocks/CU: GRID 256->512, NROW 4->2. While one
// block drains at a barrier the other computes/issues memory.
__global__ __launch_bounds__(512, 2)
void corr_volume_mfma(const float* __restrict__ left,
                      const float* __restrict__ right,
                      float* __restrict__ out) {
    __shared__ alignas(16) _Float16 Lb[256 * 64];   // [w][c^swz]      32 KiB
    __shared__ alignas(16) _Float16 Rb[320 * 64];   // [w'+64][c^swz]  40 KiB

    const int tid  = threadIdx.x;
    const int lane = tid & 63;
    const int wv   = tid >> 6;          // wave 0..7
    const int sw   = lane * 4;          // staged w rows sw..sw+3
    const int cg   = wv;                // staged channel group cg*8..cg*8+7

    const size_t chanStride = (size_t)HH * WW;      // 32768

    // Zero the w'<0 pad rows once (never overwritten; staging writes 64..319).
    {
        half8 z = {0, 0, 0, 0, 0, 0, 0, 0};
        *(half8*)&Rb[tid * 8] = z;
    }

    float4 lv[8], rv[8];

    // Prologue: issue row-0 loads immediately.
    {
        const int bh = blockIdx.x;
        const size_t rowBase = (size_t)(bh >> 7) * CC * chanStride
                             + (size_t)(bh & 127) * WW;
        const float* lp = left  + rowBase + (size_t)(cg * 8) * chanStride + sw;
        const float* rp = right + rowBase + (size_t)(cg * 8) * chanStride + sw;
        #pragma unroll
        for (int c = 0; c < 8; ++c) {
            lv[c] = *(const float4*)(lp + (size_t)c * chanStride);
            rv[c] = *(const float4*)(rp + (size_t)c * chanStride);
        }
    }

    const int n = lane & 15;            // MFMA col (w) / A row
    const int q = lane >> 4;            // quad
    const int wbase = wv * 32;          // this wave's w range
    const float scale = 1.0f / 64.0f;

    #pragma unroll
    for (int k = 0; k < NROW; ++k) {
        const int bh = blockIdx.x + k * GRID;
        const int b  = bh >> 7;
        const int h  = bh & 127;

        __syncthreads();   // prior row's LDS reads done (k=0: orders pad init)

        // Transpose 8c x 4w from regs -> LDS (waits only on this row's loads).
        {
            const float* lf = (const float*)lv;
            const float* rf = (const float*)rv;
            #pragma unroll
            for (int s = 0; s < 4; ++s) {
                const int w   = sw + s;
                const int col = (cg ^ (w & 7)) * 8;
                half8 lh, rh;
                #pragma unroll
                for (int c = 0; c < 8; ++c) {
                    lh[c] = (_Float16)lf[c * 4 + s];
                    rh[c] = (_Float16)rf[c * 4 + s];
                }
                *(half8*)&Lb[w * 64 + col]        = lh;
                *(half8*)&Rb[(w + 64) * 64 + col] = rh;
            }
        }
        __syncthreads();

        // Prefetch next row into registers — in flight through MFMA+stores.
        if (k + 1 < NROW) {
            const int bh2 = blockIdx.x + (k + 1) * GRID;
            const size_t rowBase2 = (size_t)(bh2 >> 7) * CC * chanStride
                                  + (size_t)(bh2 & 127) * WW;
            const float* lp = left  + rowBase2 + (size_t)(cg * 8) * chanStride + sw;
            const float* rp = right + rowBase2 + (size_t)(cg * 8) * chanStride + sw;
            #pragma unroll
            for (int c = 0; c < 8; ++c) {
                lv[c] = *(const float4*)(lp + (size_t)c * chanStride);
                rv[c] = *(const float4*)(rp + (size_t)c * chanStride);
            }
        }

        // ---------------- MFMA ----------------
        floatx4 acc[2][5];
        #pragma unroll
        for (int t = 0; t < 2; ++t)
            #pragma unroll
            for (int u = 0; u < 5; ++u)
                #pragma unroll
                for (int r = 0; r < 4; ++r)
                    acc[t][u][r] = 0.0f;

        #pragma unroll
        for (int kk = 0; kk < 2; ++kk) {
            const int col = ((kk * 4 + q) ^ (n & 7)) * 8;
            half8 bfrag[2], afrag[6];
            #pragma unroll
            for (int t = 0; t < 2; ++t)
                bfrag[t] = *(const half8*)&Lb[(wbase + t * 16 + n) * 64 + col];
            #pragma unroll
            for (int a = 0; a < 6; ++a)
                afrag[a] = *(const half8*)&Rb[(wbase + a * 16 + n) * 64 + col];
            #pragma unroll
            for (int t = 0; t < 2; ++t)
                #pragma unroll
                for (int u = 0; u < 5; ++u)
                    acc[t][u] = __builtin_amdgcn_mfma_f32_16x16x32_f16(
                        afrag[t + u], bfrag[t], acc[t][u], 0, 0, 0);
        }

        // ---------------- epilogue ----------------
        // C/D: col = n (w), row m = q*4+r (w' offset). d = 64-16u+n-m.
        #pragma unroll
        for (int t = 0; t < 2; ++t) {
            const int w = wbase + t * 16 + n;
            #pragma unroll
            for (int u = 0; u < 5; ++u) {
                #pragma unroll
                for (int r = 0; r < 4; ++r) {
                    const int d = 64 - 16 * u + n - (q * 4 + r);
                    if (d >= 0 && d < DD) {
                        out[(((size_t)b * DD + d) * HH + h) * WW + w] =
                            acc[t][u][r] * scale;
                    }
                }
            }
        }
    }
}

extern "C" void kernel_launch(void* const* d_in, const int* in_sizes, int n_in,
                              void* d_out, int out_size, void* d_ws, size_t ws_size,
                              hipStream_t stream) {
    const float* left  = (const float*)d_in[0];
    const float* right = (const float*)d_in[1];
    float* out = (float*)d_out;

    dim3 grid(GRID);    // 512 blocks = 2 per CU, each pipelines NROW rows
    dim3 block(512);
    corr_volume_mfma<<<grid, block, 0, stream>>>(left, right, out);
}

// Round 2
// 171.875 us; speedup vs baseline: 1.1114x; 1.1114x over previous
//
#include <hip/hip_runtime.h>

typedef _Float16 half8 __attribute__((ext_vector_type(8)));
typedef float floatx4 __attribute__((ext_vector_type(4)));

#define BB 8
#define CC 64
#define HH 128
#define WW 256
#define DD 64
#define NROW 2            // (b,h) rows per block
#define GRID 512          // 2 blocks per CU; NROW*GRID == BB*HH
#define OPITCH 260        // Ob row pitch (floats): bank=(4d+w)&31 -> 2 lanes/bank

// out[b,d,h,w] = (1/64) sum_c L[b,c,h,w] * R[b,c,h,w-d], 0 where w<d.
// Banded Gram via mfma_f32_16x16x32_f16 (see R3/R4 comments for the algebra).
// R6: 2 blocks/CU — NULL result (per-CU row throughput unchanged) => shared
// memory-path resource saturated, not latency.
// R7: coalesced epilogue. rocprof showed FETCH_SIZE ~= WRITE_SIZE ~= 66 MB:
// the scattered 4B stores (lane stride ~128KB+4: d AND w vary per lane) hit
// one distinct 64B line per lane => L2 read-for-ownership fetches every
// output line from HBM (67 MB pure overhead) and ~16.7M line transactions
// serialize the store path per-CU (invariant to blocks/CU — matches R6).
// Fix: after MFMA, overlay Ob[64][260] floats on the dead Lb/Rb LDS, write
// acc -> Ob[d][w] (pitch 260 => conflict-free), then each wave stores full
// 1KB d-rows with dwordx4 (full-line writes: no RFO, 16x fewer line txns).
// Next-row prefetch moved after the Ob-fill barrier to overlap store phase.
__global__ __launch_bounds__(512, 2)
void corr_volume_mfma(const float* __restrict__ left,
                      const float* __restrict__ right,
                      float* __restrict__ out) {
    // 72 KiB arena: phase 1 = Lb[256*64] (32K) + Rb[320*64] (40K) halves;
    // phase 2 (epilogue) overlays Ob[64][OPITCH] floats (66,560 B).
    __shared__ alignas(16) unsigned char smem[73728];
    _Float16* const Lb = (_Float16*)smem;
    _Float16* const Rb = (_Float16*)(smem + 32768);
    float*    const Ob = (float*)smem;

    const int tid  = threadIdx.x;
    const int lane = tid & 63;
    const int wv   = tid >> 6;          // wave 0..7
    const int sw   = lane * 4;          // staged w rows sw..sw+3
    const int cg   = wv;                // staged channel group cg*8..cg*8+7

    const size_t chanStride = (size_t)HH * WW;      // 32768

    float4 lv[8], rv[8];

    // Prologue: issue row-0 loads immediately.
    {
        const int bh = blockIdx.x;
        const size_t rowBase = (size_t)(bh >> 7) * CC * chanStride
                             + (size_t)(bh & 127) * WW;
        const float* lp = left  + rowBase + (size_t)(cg * 8) * chanStride + sw;
        const float* rp = right + rowBase + (size_t)(cg * 8) * chanStride + sw;
        #pragma unroll
        for (int c = 0; c < 8; ++c) {
            lv[c] = *(const float4*)(lp + (size_t)c * chanStride);
            rv[c] = *(const float4*)(rp + (size_t)c * chanStride);
        }
    }

    const int n = lane & 15;            // MFMA col (w) / A row
    const int q = lane >> 4;            // quad
    const int wbase = wv * 32;          // this wave's w range
    const float scale = 1.0f / 64.0f;

    #pragma unroll
    for (int k = 0; k < NROW; ++k) {
        const int bh = blockIdx.x + k * GRID;
        const int b  = bh >> 7;
        const int h  = bh & 127;

        __syncthreads();   // A: prior row's Ob reads done (k=0: no-op)

        // Re-zero the w'<0 pad rows (Ob overlay clobbers them every row).
        {
            half8 z = {0, 0, 0, 0, 0, 0, 0, 0};
            *(half8*)&Rb[tid * 8] = z;
        }

        // Transpose 8c x 4w from regs -> LDS (waits only on this row's loads).
        {
            const float* lf = (const float*)lv;
            const float* rf = (const float*)rv;
            #pragma unroll
            for (int s = 0; s < 4; ++s) {
                const int w   = sw + s;
                const int col = (cg ^ (w & 7)) * 8;
                half8 lh, rh;
                #pragma unroll
                for (int c = 0; c < 8; ++c) {
                    lh[c] = (_Float16)lf[c * 4 + s];
                    rh[c] = (_Float16)rf[c * 4 + s];
                }
                *(half8*)&Lb[w * 64 + col]        = lh;
                *(half8*)&Rb[(w + 64) * 64 + col] = rh;
            }
        }
        __syncthreads();   // B: tiles staged

        // ---------------- MFMA ----------------
        floatx4 acc[2][5];
        #pragma unroll
        for (int t = 0; t < 2; ++t)
            #pragma unroll
            for (int u = 0; u < 5; ++u)
                #pragma unroll
                for (int r = 0; r < 4; ++r)
                    acc[t][u][r] = 0.0f;

        #pragma unroll
        for (int kk = 0; kk < 2; ++kk) {
            const int col = ((kk * 4 + q) ^ (n & 7)) * 8;
            half8 bfrag[2], afrag[6];
            #pragma unroll
            for (int t = 0; t < 2; ++t)
                bfrag[t] = *(const half8*)&Lb[(wbase + t * 16 + n) * 64 + col];
            #pragma unroll
            for (int a = 0; a < 6; ++a)
                afrag[a] = *(const half8*)&Rb[(wbase + a * 16 + n) * 64 + col];
            #pragma unroll
            for (int t = 0; t < 2; ++t)
                #pragma unroll
                for (int u = 0; u < 5; ++u)
                    acc[t][u] = __builtin_amdgcn_mfma_f32_16x16x32_f16(
                        afrag[t + u], bfrag[t], acc[t][u], 0, 0, 0);
        }
        __syncthreads();   // C: all waves' fragment reads done; Lb/Rb dead

        // acc -> Ob[d][w]. C/D: col = n (w), row m = q*4+r. d = 64-16u+n-m.
        // bank = (4d+w)&31 = C + 5n + 16(q&1): all 32 banks, 2 lanes each.
        #pragma unroll
        for (int t = 0; t < 2; ++t) {
            const int w = wbase + t * 16 + n;
            #pragma unroll
            for (int u = 0; u < 5; ++u) {
                #pragma unroll
                for (int r = 0; r < 4; ++r) {
                    const int d = 64 - 16 * u + n - (q * 4 + r);
                    if (d >= 0 && d < DD) {
                        Ob[d * OPITCH + w] = acc[t][u][r] * scale;
                    }
                }
            }
        }
        __syncthreads();   // D: Ob complete

        // Prefetch next row — issued before the store phase so the HBM/LLC
        // latency hides under 8 ds_read+store pairs; drained at next A.
        if (k + 1 < NROW) {
            const int bh2 = blockIdx.x + (k + 1) * GRID;
            const size_t rowBase2 = (size_t)(bh2 >> 7) * CC * chanStride
                                  + (size_t)(bh2 & 127) * WW;
            const float* lp = left  + rowBase2 + (size_t)(cg * 8) * chanStride + sw;
            const float* rp = right + rowBase2 + (size_t)(cg * 8) * chanStride + sw;
            #pragma unroll
            for (int c = 0; c < 8; ++c) {
                lv[c] = *(const float4*)(lp + (size_t)c * chanStride);
                rv[c] = *(const float4*)(rp + (size_t)c * chanStride);
            }
        }

        // Coalesced stores: wave wv owns d = wv*8 .. wv*8+7; each instruction
        // writes one full 1KB row (lane l at byte offset l*16) — no RFO.
        #pragma unroll
        for (int i = 0; i < 8; ++i) {
            const int d = wv * 8 + i;
            const float4 v = *(const float4*)&Ob[d * OPITCH + lane * 4];
            *(float4*)&out[(((size_t)b * DD + d) * HH + h) * WW + lane * 4] = v;
        }
    }
}

extern "C" void kernel_launch(void* const* d_in, const int* in_sizes, int n_in,
                              void* d_out, int out_size, void* d_ws, size_t ws_size,
                              hipStream_t stream) {
    const float* left  = (const float*)d_in[0];
    const float* right = (const float*)d_in[1];
    float* out = (float*)d_out;

    dim3 grid(GRID);    // 512 blocks = 2 per CU, each pipelines NROW rows
    dim3 block(512);
    corr_volume_mfma<<<grid, block, 0, stream>>>(left, right, out);
}